// Round 2
// baseline (5759.701 us; speedup 1.0000x reference)
//
#include <hip/hip_runtime.h>
#include <hip/hip_bf16.h>
#include <math.h>

// dims
#define BB   2
#define SS   1024
#define DD   1024
#define HH   16
#define DHH  64
#define DFFD 4096
#define LL   2
#define VV   32000
#define GSZ  128
#define BSR  (BB*SS)   // 2048 rows
constexpr float EPS = 1e-6f;

// ---------------- embedding: x[row,:] = t[id,:] * s[id, d/128] ----------------
__global__ __launch_bounds__(256) void k_embed(const int* __restrict__ ids,
                                               const int* __restrict__ t,
                                               const float* __restrict__ s,
                                               float* __restrict__ x) {
    int row = blockIdx.x;                 // 0..BSR-1
    int id  = ids[row];
    for (int d = threadIdx.x; d < DD; d += 256) {
        x[(size_t)row * DD + d] =
            (float)t[(size_t)id * DD + d] * s[id * (DD / GSZ) + (d >> 7)];
    }
}

// ---------------- rmsnorm: o = x * rsqrt(mean(x^2)+eps) * w ----------------
__global__ __launch_bounds__(256) void k_rmsnorm(const float* __restrict__ x,
                                                 const float* __restrict__ w,
                                                 float* __restrict__ o) {
    int row = blockIdx.x;
    const float* xr = x + (size_t)row * DD;
    float ss = 0.f;
    for (int d = threadIdx.x; d < DD; d += 256) { float v = xr[d]; ss += v * v; }
    __shared__ float sm[4];
    for (int off = 32; off > 0; off >>= 1) ss += __shfl_down(ss, off, 64);
    if ((threadIdx.x & 63) == 0) sm[threadIdx.x >> 6] = ss;
    __syncthreads();
    float tot = sm[0] + sm[1] + sm[2] + sm[3];
    float inv = rsqrtf(tot / DD + EPS);
    for (int d = threadIdx.x; d < DD; d += 256) o[(size_t)row * DD + d] = xr[d] * inv * w[d];
}

// ---------------- dequant GEMM: C[i,o] = sum_k A[i,k]*t[o,k]*s[o*(K/GS)+k/128] ----------------
// MODE: 0 = store, 1 = add into C, 2 = swiglu: C = silu(C) * acc
// 64x64 tile, BK=16, 256 threads as 16x16, each 4x4 microtile.
template <int MODE>
__global__ __launch_bounds__(256) void gemm_dq(const float* __restrict__ A,
                                               const int* __restrict__ T,
                                               const float* __restrict__ Sg,
                                               float* __restrict__ C,
                                               int M, int N, int K) {
    const int i0 = blockIdx.y * 64;
    const int o0 = blockIdx.x * 64;
    __shared__ float As[16][68];   // [k][m]
    __shared__ float Bs[16][68];   // [k][o]
    const int tid = threadIdx.x;
    const int tm = tid >> 4, tn = tid & 15;
    const int kg = K / GSZ;
    float acc[4][4] = {};
    const int c = tid & 15;        // k within tile
    const int r = tid >> 4;        // row base
    for (int k0 = 0; k0 < K; k0 += 16) {
        const int g = k0 >> 7;     // scale group (constant over 16-wide k tile)
#pragma unroll
        for (int it = 0; it < 4; ++it) {
            int mi = r + 16 * it;
            As[c][mi] = A[(size_t)(i0 + mi) * K + k0 + c];
            int o = o0 + mi;
            Bs[c][mi] = (float)T[(size_t)o * K + k0 + c] * Sg[(size_t)o * kg + g];
        }
        __syncthreads();
#pragma unroll
        for (int kk = 0; kk < 16; ++kk) {
            float a[4], b[4];
#pragma unroll
            for (int xx = 0; xx < 4; ++xx) a[xx] = As[kk][tm * 4 + xx];
#pragma unroll
            for (int yy = 0; yy < 4; ++yy) b[yy] = Bs[kk][tn * 4 + yy];
#pragma unroll
            for (int xx = 0; xx < 4; ++xx)
#pragma unroll
                for (int yy = 0; yy < 4; ++yy) acc[xx][yy] += a[xx] * b[yy];
        }
        __syncthreads();
    }
#pragma unroll
    for (int xx = 0; xx < 4; ++xx) {
        size_t i = i0 + tm * 4 + xx;
#pragma unroll
        for (int yy = 0; yy < 4; ++yy) {
            size_t o = o0 + tn * 4 + yy;
            if (MODE == 0) {
                C[i * N + o] = acc[xx][yy];
            } else if (MODE == 1) {
                C[i * N + o] += acc[xx][yy];
            } else {               // swiglu: C holds gate pre-act, acc = up value
                float gv = C[i * N + o];
                C[i * N + o] = gv / (1.f + __expf(-gv)) * acc[xx][yy];
            }
        }
    }
}

// ---------------- attention: one block per (b,h,sq) row ----------------
__global__ __launch_bounds__(256) void k_attn(const float* __restrict__ q,
                                              const float* __restrict__ k,
                                              const float* __restrict__ v,
                                              const float* __restrict__ hn,
                                              const float* __restrict__ alpha,
                                              float* __restrict__ out) {
    const int bid = blockIdx.x;
    const int sq = bid & (SS - 1);
    const int bh = bid >> 10;            // S = 1024
    const int hh = bh & (HH - 1);
    const int b  = bh >> 4;
    const int tid = threadIdx.x;

    __shared__ float qrow[DHH];
    __shared__ float Kt[64][65];
    __shared__ float p[SS];
    __shared__ float psum[4][64];
    __shared__ float red[4];
    __shared__ float bcast[2];

    const size_t rowbase = (size_t)(b * SS + sq) * DD + hh * DHH;
    const size_t kvbase  = (size_t)b * SS * DD + hh * DHH;
    if (tid < DHH) qrow[tid] = q[rowbase + tid];

    const int nt = sq + 1;
    const int ntiles = (nt + 63) >> 6;
    const int part = tid >> 6;           // 0..3
    const int lane = tid & 63;

    // ---- pass A: scores ----
    for (int tile = 0; tile < ntiles; ++tile) {
        const int base = tile * 64;
#pragma unroll
        for (int it = 0; it < 4; ++it) {
            int l = tid + 256 * it;      // 1024 float4 quads
            int rr = l >> 4, c4 = l & 15;
            float4 kv = *(const float4*)(k + kvbase + (size_t)(base + rr) * DD + c4 * 4);
            Kt[rr][c4 * 4 + 0] = kv.x; Kt[rr][c4 * 4 + 1] = kv.y;
            Kt[rr][c4 * 4 + 2] = kv.z; Kt[rr][c4 * 4 + 3] = kv.w;
        }
        __syncthreads();
        float partial = 0.f;
#pragma unroll
        for (int j = 0; j < 16; ++j) partial += qrow[part * 16 + j] * Kt[lane][part * 16 + j];
        psum[part][lane] = partial;
        __syncthreads();
        if (tid < 64) {
            int t = base + tid;
            if (t < nt)
                p[t] = (psum[0][tid] + psum[1][tid] + psum[2][tid] + psum[3][tid]) * 0.125f;
        }
        __syncthreads();
    }

    // ---- softmax ----
    float lm = -1e30f;
    for (int t = tid; t < nt; t += 256) lm = fmaxf(lm, p[t]);
    for (int off = 32; off > 0; off >>= 1) lm = fmaxf(lm, __shfl_down(lm, off, 64));
    if (lane == 0) red[part] = lm;
    __syncthreads();
    if (tid == 0) bcast[0] = fmaxf(fmaxf(red[0], red[1]), fmaxf(red[2], red[3]));
    __syncthreads();
    const float m = bcast[0];
    float ls = 0.f;
    for (int t = tid; t < nt; t += 256) { float e = __expf(p[t] - m); p[t] = e; ls += e; }
    for (int off = 32; off > 0; off >>= 1) ls += __shfl_down(ls, off, 64);
    if (lane == 0) red[part] = ls;
    __syncthreads();
    if (tid == 0) bcast[1] = red[0] + red[1] + red[2] + red[3];
    __syncthreads();
    const float inv = 1.f / bcast[1];

    // ---- pass B: o = p @ V ----
    float oacc = 0.f;
    const int dh = lane;
    for (int tile = 0; tile < ntiles; ++tile) {
        const int base = tile * 64;
#pragma unroll
        for (int it = 0; it < 4; ++it) {
            int l = tid + 256 * it;
            int rr = l >> 4, c4 = l & 15;
            float4 vv = *(const float4*)(v + kvbase + (size_t)(base + rr) * DD + c4 * 4);
            Kt[rr][c4 * 4 + 0] = vv.x; Kt[rr][c4 * 4 + 1] = vv.y;
            Kt[rr][c4 * 4 + 2] = vv.z; Kt[rr][c4 * 4 + 3] = vv.w;
        }
        __syncthreads();
        const int tmax = nt - base;           // >= 1
        const int jend = min(part * 16 + 16, tmax);
        for (int j = part * 16; j < jend; ++j) oacc += p[base + j] * Kt[j][dh];
        __syncthreads();
    }
    psum[part][dh] = oacc;
    __syncthreads();
    if (tid < 64) {
        float o = psum[0][tid] + psum[1][tid] + psum[2][tid] + psum[3][tid];
        out[rowbase + tid] = o * inv + alpha[hh] * hn[rowbase + tid];
    }
}

extern "C" void kernel_launch(void* const* d_in, const int* in_sizes, int n_in,
                              void* d_out, int out_size, void* d_ws, size_t ws_size,
                              hipStream_t stream) {
    const int*   ids   = (const int*)d_in[0];
    const int*   emb_t = (const int*)d_in[1];
    const float* emb_s = (const float*)d_in[2];
    const int*   qt    = (const int*)d_in[3];
    const float* qs    = (const float*)d_in[4];
    const int*   kt    = (const int*)d_in[5];
    const float* ks    = (const float*)d_in[6];
    const int*   vt    = (const int*)d_in[7];
    const float* vs    = (const float*)d_in[8];
    const int*   ot    = (const int*)d_in[9];
    const float* os    = (const float*)d_in[10];
    const int*   gatet = (const int*)d_in[11];
    const float* gates = (const float*)d_in[12];
    const int*   upt   = (const int*)d_in[13];
    const float* ups   = (const float*)d_in[14];
    const int*   downt = (const int*)d_in[15];
    const float* downs = (const float*)d_in[16];
    const float* wa    = (const float*)d_in[17];
    const float* wm    = (const float*)d_in[18];
    const float* alpha = (const float*)d_in[19];
    const float* wf    = (const float*)d_in[20];
    const int*   headt = (const int*)d_in[21];
    const float* heads = (const float*)d_in[22];

    // workspace layout (floats): x, h, qb, kb, vb, ao (each BSR*D) + g (BSR*DFF)
    float* x  = (float*)d_ws;            // [BSR, D]
    float* h  = x  + (size_t)BSR * DD;   // [BSR, D]  normed
    float* qb = h  + (size_t)BSR * DD;   // [B,S,H,DH]
    float* kb = qb + (size_t)BSR * DD;
    float* vb = kb + (size_t)BSR * DD;
    float* ao = vb + (size_t)BSR * DD;   // attention out [BSR, D]
    float* g  = ao + (size_t)BSR * DD;   // [BSR, DFF] gate -> swiglu result

    const size_t wDD  = (size_t)DD * DD;        // per-layer qkvo stride
    const size_t sDD  = wDD / GSZ;
    const size_t wFD  = (size_t)DFFD * DD;      // per-layer gate/up/down stride
    const size_t sFD  = wFD / GSZ;

    k_embed<<<BSR, 256, 0, stream>>>(ids, emb_t, emb_s, x);

    dim3 gD(DD / 64, BSR / 64);
    dim3 gF(DFFD / 64, BSR / 64);
    for (int l = 0; l < LL; ++l) {
        k_rmsnorm<<<BSR, 256, 0, stream>>>(x, wa + l * DD, h);
        gemm_dq<0><<<gD, 256, 0, stream>>>(h, qt + l * wDD, qs + l * sDD, qb, BSR, DD, DD);
        gemm_dq<0><<<gD, 256, 0, stream>>>(h, kt + l * wDD, ks + l * sDD, kb, BSR, DD, DD);
        gemm_dq<0><<<gD, 256, 0, stream>>>(h, vt + l * wDD, vs + l * sDD, vb, BSR, DD, DD);
        k_attn<<<BB * HH * SS, 256, 0, stream>>>(qb, kb, vb, h, alpha + l * HH, ao);
        gemm_dq<1><<<gD, 256, 0, stream>>>(ao, ot + l * wDD, os + l * sDD, x, BSR, DD, DD);

        k_rmsnorm<<<BSR, 256, 0, stream>>>(x, wm + l * DD, h);
        gemm_dq<0><<<gF, 256, 0, stream>>>(h, gatet + l * wFD, gates + l * sFD, g, BSR, DFFD, DD);
        gemm_dq<2><<<gF, 256, 0, stream>>>(h, upt + l * wFD, ups + l * sFD, g, BSR, DFFD, DD);
        gemm_dq<1><<<gD, 256, 0, stream>>>(g, downt + l * wFD, downs + l * sFD, x, BSR, DD, DFFD);
    }

    k_rmsnorm<<<BSR, 256, 0, stream>>>(x, wf, h);
    dim3 gV(VV / 64, BSR / 64);
    gemm_dq<0><<<gV, 256, 0, stream>>>(h, headt, heads, (float*)d_out, BSR, VV, DD);
}

// Round 3
// 2234.219 us; speedup vs baseline: 2.5779x; 2.5779x over previous
//
#include <hip/hip_runtime.h>
#include <math.h>
#include <stdint.h>

// dims
#define BB   2
#define SS   1024
#define DD   1024
#define HH   16
#define DHH  64
#define DFFD 4096
#define LL   2
#define VV   32000
#define GSZ  128
#define BSR  (BB*SS)   // 2048 rows
constexpr float EPS = 1e-6f;

typedef unsigned short ushort_t;
typedef __bf16 bf16x8 __attribute__((ext_vector_type(8)));
typedef short  short8 __attribute__((ext_vector_type(8)));
typedef float  f32x4  __attribute__((ext_vector_type(4)));

__device__ inline ushort_t f2bf(float f) {
    unsigned int u = __builtin_bit_cast(unsigned int, f);
    unsigned int r = u + 0x7fffu + ((u >> 16) & 1u);
    return (ushort_t)(r >> 16);
}
__device__ inline float bf2f(ushort_t u) {
    unsigned int x = ((unsigned int)u) << 16;
    return __builtin_bit_cast(float, x);
}

#define GL2L(g, l) __builtin_amdgcn_global_load_lds( \
    (const __attribute__((address_space(1))) void*)(g), \
    (__attribute__((address_space(3))) void*)(l), 16, 0, 0)

// ---------------- dequant: W[i] = bf16(T[i] * S[i/128]) ----------------
__global__ __launch_bounds__(256) void k_dequant(const int* __restrict__ T,
                                                 const float* __restrict__ S,
                                                 ushort_t* __restrict__ W) {
    int i = (blockIdx.x * 256 + threadIdx.x) * 4;
    int4 t = *(const int4*)(T + i);
    float s = S[i >> 7];
    ushort4 w;
    w.x = f2bf((float)t.x * s); w.y = f2bf((float)t.y * s);
    w.z = f2bf((float)t.z * s); w.w = f2bf((float)t.w * s);
    *(ushort4*)(W + i) = w;
}

// ---------------- embedding: x[row,:] = t[id,:] * s[id, d/128] (fp32) ----------------
__global__ __launch_bounds__(256) void k_embed(const int* __restrict__ ids,
                                               const int* __restrict__ t,
                                               const float* __restrict__ s,
                                               float* __restrict__ x) {
    int row = blockIdx.x;
    int id  = ids[row];
    for (int d = threadIdx.x; d < DD; d += 256) {
        x[(size_t)row * DD + d] =
            (float)t[(size_t)id * DD + d] * s[id * (DD / GSZ) + (d >> 7)];
    }
}

// ---------------- rmsnorm: o = bf16(x * rsqrt(mean(x^2)+eps) * w) ----------------
__global__ __launch_bounds__(256) void k_rmsnorm(const float* __restrict__ x,
                                                 const float* __restrict__ w,
                                                 ushort_t* __restrict__ o) {
    int row = blockIdx.x;
    const float* xr = x + (size_t)row * DD;
    float ss = 0.f;
    for (int d = threadIdx.x; d < DD; d += 256) { float v = xr[d]; ss += v * v; }
    __shared__ float sm[4];
    for (int off = 32; off > 0; off >>= 1) ss += __shfl_down(ss, off, 64);
    if ((threadIdx.x & 63) == 0) sm[threadIdx.x >> 6] = ss;
    __syncthreads();
    float tot = sm[0] + sm[1] + sm[2] + sm[3];
    float inv = rsqrtf(tot / DD + EPS);
    for (int d = threadIdx.x; d < DD; d += 256)
        o[(size_t)row * DD + d] = f2bf(xr[d] * inv * w[d]);
}

// ---------------- bf16 MFMA GEMM: C[M,N] = A[M,K] @ W[N,K]^T ----------------
// m97 structure: 128x128 tile, BK=32, 256 thr = 4 waves, each wave 64x64 via
// 4x4 grid of mfma_f32_16x16x32_bf16. global_load_lds width=16 staging.
// MODE: 0 = store f32, 1 = add f32, 2 = swiglu(read Gf, write bf16), 3 = store bf16
template <int MODE>
__global__ __launch_bounds__(256) void gemm_bf16(const ushort_t* __restrict__ A,
                                                 const ushort_t* __restrict__ W,
                                                 float* __restrict__ Cf,
                                                 ushort_t* __restrict__ Cb,
                                                 const float* __restrict__ Gf,
                                                 int M, int N, int K) {
    __shared__ ushort_t As[128 * 32];
    __shared__ ushort_t Bs[128 * 32];
    const int tid  = threadIdx.x;
    const int wave = tid >> 6, lane = tid & 63;
    const int wm = wave >> 1, wn = wave & 1;
    const int i0 = blockIdx.y * 128, o0 = blockIdx.x * 128;

    f32x4 acc[4][4] = {};

    // staging: per wave, 2 calls for A + 2 for B; call covers 16 rows x 32 cols
    const int srow = wave * 32 + (lane >> 2);
    const int scol = (lane & 3) * 8;
    const ushort_t* aG0 = A + (size_t)(i0 + srow) * K + scol;
    const ushort_t* aG1 = aG0 + (size_t)16 * K;
    const ushort_t* bG0 = W + (size_t)(o0 + srow) * K + scol;
    const ushort_t* bG1 = bG0 + (size_t)16 * K;
    ushort_t* aL0 = As + wave * 1024;
    ushort_t* aL1 = aL0 + 512;
    ushort_t* bL0 = Bs + wave * 1024;
    ushort_t* bL1 = bL0 + 512;

    // fragment read base: A[m=lane&15][k=(lane>>4)*8 + j]
    const ushort_t* ap = As + (wm * 64 + (lane & 15)) * 32 + (lane >> 4) * 8;
    const ushort_t* bp = Bs + (wn * 64 + (lane & 15)) * 32 + (lane >> 4) * 8;

    for (int k0 = 0; k0 < K; k0 += 32) {
        __syncthreads();
        GL2L(aG0 + k0, aL0);
        GL2L(aG1 + k0, aL1);
        GL2L(bG0 + k0, bL0);
        GL2L(bG1 + k0, bL1);
        __syncthreads();
        bf16x8 av[4], bv[4];
#pragma unroll
        for (int t = 0; t < 4; ++t) {
            av[t] = __builtin_bit_cast(bf16x8, *(const short8*)(ap + t * 512));
            bv[t] = __builtin_bit_cast(bf16x8, *(const short8*)(bp + t * 512));
        }
#pragma unroll
        for (int mt = 0; mt < 4; ++mt)
#pragma unroll
            for (int nt = 0; nt < 4; ++nt)
                acc[mt][nt] = __builtin_amdgcn_mfma_f32_16x16x32_bf16(
                    av[mt], bv[nt], acc[mt][nt], 0, 0, 0);
    }

    // epilogue: C/D layout col=lane&15, row=(lane>>4)*4+reg
    const int r0 = wm * 64 + (lane >> 4) * 4;
    const int c0 = wn * 64 + (lane & 15);
#pragma unroll
    for (int mt = 0; mt < 4; ++mt) {
#pragma unroll
        for (int r = 0; r < 4; ++r) {
            const size_t row = i0 + r0 + mt * 16 + r;
#pragma unroll
            for (int nt = 0; nt < 4; ++nt) {
                const size_t col = o0 + c0 + nt * 16;
                const size_t idx = row * (size_t)N + col;
                float v = acc[mt][nt][r];
                if (MODE == 0) {
                    Cf[idx] = v;
                } else if (MODE == 1) {
                    Cf[idx] += v;
                } else if (MODE == 2) {
                    float gv = Gf[idx];
                    Cb[idx] = f2bf(gv / (1.f + __expf(-gv)) * v);
                } else {
                    Cb[idx] = f2bf(v);
                }
            }
        }
    }
}

// ---------------- attention: one block per (b,h,sq) row; bf16 in/out ----------------
// qkv: [BSR, 3*D] fused (q | k | v). hn: [BSR, D]. out: [BSR, D] bf16.
__global__ __launch_bounds__(256) void k_attn(const ushort_t* __restrict__ qkv,
                                              const ushort_t* __restrict__ hn,
                                              const float* __restrict__ alpha,
                                              ushort_t* __restrict__ out) {
    const int bid = blockIdx.x;
    const int sq = bid & (SS - 1);
    const int bh = bid >> 10;
    const int hh = bh & (HH - 1);
    const int b  = bh >> 4;
    const int tid = threadIdx.x;

    __shared__ float qrow[DHH];
    __shared__ float Kt[64][65];
    __shared__ float p[SS];
    __shared__ float psum[4][64];
    __shared__ float red[4];
    __shared__ float bcast[2];

    const int bS0 = b * SS;
    const size_t qbase = (size_t)(bS0 + sq) * 3072 + hh * DHH;
    if (tid < DHH) qrow[tid] = bf2f(qkv[qbase + tid]);

    const int nt = sq + 1;
    const int ntiles = (nt + 63) >> 6;
    const int part = tid >> 6;
    const int lane = tid & 63;

    // ---- pass A: scores ----
    for (int tile = 0; tile < ntiles; ++tile) {
        const int base = tile * 64;
#pragma unroll
        for (int it = 0; it < 4; ++it) {
            int l = tid + 256 * it;
            int rr = l >> 4, c4 = (l & 15) * 4;
            ushort4 kv = *(const ushort4*)(qkv + (size_t)(bS0 + base + rr) * 3072
                                               + 1024 + hh * DHH + c4);
            Kt[rr][c4 + 0] = bf2f(kv.x); Kt[rr][c4 + 1] = bf2f(kv.y);
            Kt[rr][c4 + 2] = bf2f(kv.z); Kt[rr][c4 + 3] = bf2f(kv.w);
        }
        __syncthreads();
        float partial = 0.f;
#pragma unroll
        for (int j = 0; j < 16; ++j) partial += qrow[part * 16 + j] * Kt[lane][part * 16 + j];
        psum[part][lane] = partial;
        __syncthreads();
        if (tid < 64) {
            int t = base + tid;
            if (t < nt)
                p[t] = (psum[0][tid] + psum[1][tid] + psum[2][tid] + psum[3][tid]) * 0.125f;
        }
        __syncthreads();
    }

    // ---- softmax ----
    float lm = -1e30f;
    for (int t = tid; t < nt; t += 256) lm = fmaxf(lm, p[t]);
    for (int off = 32; off > 0; off >>= 1) lm = fmaxf(lm, __shfl_down(lm, off, 64));
    if (lane == 0) red[part] = lm;
    __syncthreads();
    if (tid == 0) bcast[0] = fmaxf(fmaxf(red[0], red[1]), fmaxf(red[2], red[3]));
    __syncthreads();
    const float m = bcast[0];
    float ls = 0.f;
    for (int t = tid; t < nt; t += 256) { float e = __expf(p[t] - m); p[t] = e; ls += e; }
    for (int off = 32; off > 0; off >>= 1) ls += __shfl_down(ls, off, 64);
    if (lane == 0) red[part] = ls;
    __syncthreads();
    if (tid == 0) bcast[1] = red[0] + red[1] + red[2] + red[3];
    __syncthreads();
    const float inv = 1.f / bcast[1];

    // ---- pass B: o = p @ V ----
    float oacc = 0.f;
    const int dh = lane;
    for (int tile = 0; tile < ntiles; ++tile) {
        const int base = tile * 64;
#pragma unroll
        for (int it = 0; it < 4; ++it) {
            int l = tid + 256 * it;
            int rr = l >> 4, c4 = (l & 15) * 4;
            ushort4 vv = *(const ushort4*)(qkv + (size_t)(bS0 + base + rr) * 3072
                                               + 2048 + hh * DHH + c4);
            Kt[rr][c4 + 0] = bf2f(vv.x); Kt[rr][c4 + 1] = bf2f(vv.y);
            Kt[rr][c4 + 2] = bf2f(vv.z); Kt[rr][c4 + 3] = bf2f(vv.w);
        }
        __syncthreads();
        const int tmax = nt - base;
        const int jend = min(part * 16 + 16, tmax);
        for (int j = part * 16; j < jend; ++j) oacc += p[base + j] * Kt[j][dh];
        __syncthreads();
    }
    psum[part][dh] = oacc;
    __syncthreads();
    if (tid < 64) {
        float o = psum[0][tid] + psum[1][tid] + psum[2][tid] + psum[3][tid];
        size_t obase = (size_t)(bS0 + sq) * DD + hh * DHH;
        out[obase + tid] = f2bf(o * inv + alpha[hh] * bf2f(hn[obase + tid]));
    }
}

extern "C" void kernel_launch(void* const* d_in, const int* in_sizes, int n_in,
                              void* d_out, int out_size, void* d_ws, size_t ws_size,
                              hipStream_t stream) {
    const int*   ids   = (const int*)d_in[0];
    const int*   emb_t = (const int*)d_in[1];
    const float* emb_s = (const float*)d_in[2];
    const int*   qt    = (const int*)d_in[3];
    const float* qs    = (const float*)d_in[4];
    const int*   kt    = (const int*)d_in[5];
    const float* ks    = (const float*)d_in[6];
    const int*   vt    = (const int*)d_in[7];
    const float* vs    = (const float*)d_in[8];
    const int*   ot    = (const int*)d_in[9];
    const float* os    = (const float*)d_in[10];
    const int*   gatet = (const int*)d_in[11];
    const float* gates = (const float*)d_in[12];
    const int*   upt   = (const int*)d_in[13];
    const float* ups   = (const float*)d_in[14];
    const int*   downt = (const int*)d_in[15];
    const float* downs = (const float*)d_in[16];
    const float* wa    = (const float*)d_in[17];
    const float* wm    = (const float*)d_in[18];
    const float* alpha = (const float*)d_in[19];
    const float* wf    = (const float*)d_in[20];
    const int*   headt = (const int*)d_in[21];
    const float* heads = (const float*)d_in[22];

    // ---- workspace layout (byte offsets; region [0,75MB) is time-aliased) ----
    // wbuf: dequantized weights for the CURRENT gemm (head needs 65.54MB)
    // g:    gate pre-act fp32 (dead before head dequant)
    // gb:   swiglu out bf16   (dead before head dequant)
    const size_t MB = 1ull << 20;
    char* wsb = (char*)d_ws;
    ushort_t* wbuf = (ushort_t*)(wsb);            // <= 65.6MB
    float*    g    = (float*)   (wsb + 24 * MB);  // 33.6MB
    ushort_t* gb   = (ushort_t*)(wsb + 58 * MB);  // 16.8MB
    float*    x    = (float*)   (wsb + 75 * MB);  // 8.4MB
    ushort_t* h    = (ushort_t*)(wsb + 84 * MB);  // 4.2MB
    ushort_t* qkvb = (ushort_t*)(wsb + 89 * MB);  // 12.6MB  [BSR, 3072]
    ushort_t* ao   = (ushort_t*)(wsb + 102 * MB); // 4.2MB   ends ~106.2MB

    const size_t wDD = (size_t)DD * DD;       // 1M elems
    const size_t sDD = wDD / GSZ;
    const size_t wFD = (size_t)DFFD * DD;     // 4M elems
    const size_t sFD = wFD / GSZ;

    k_embed<<<BSR, 256, 0, stream>>>(ids, emb_t, emb_s, x);

    const dim3 gQKV(3072 / 128, BSR / 128);   // 24 x 16
    const dim3 gD(DD / 128, BSR / 128);       // 8 x 16
    const dim3 gF(DFFD / 128, BSR / 128);     // 32 x 16
    const dim3 gV(VV / 128, BSR / 128);       // 250 x 16

    for (int l = 0; l < LL; ++l) {
        k_rmsnorm<<<BSR, 256, 0, stream>>>(x, wa + l * DD, h);
        // fused QKV weights -> wbuf [3072, 1024]
        k_dequant<<<wDD / 1024, 256, 0, stream>>>(qt + l * wDD, qs + l * sDD, wbuf);
        k_dequant<<<wDD / 1024, 256, 0, stream>>>(kt + l * wDD, ks + l * sDD, wbuf + wDD);
        k_dequant<<<wDD / 1024, 256, 0, stream>>>(vt + l * wDD, vs + l * sDD, wbuf + 2 * wDD);
        gemm_bf16<3><<<gQKV, 256, 0, stream>>>(h, wbuf, nullptr, qkvb, nullptr, BSR, 3072, DD);
        k_attn<<<BB * HH * SS, 256, 0, stream>>>(qkvb, h, alpha + l * HH, ao);
        k_dequant<<<wDD / 1024, 256, 0, stream>>>(ot + l * wDD, os + l * sDD, wbuf);
        gemm_bf16<1><<<gD, 256, 0, stream>>>(ao, wbuf, x, nullptr, nullptr, BSR, DD, DD);

        k_rmsnorm<<<BSR, 256, 0, stream>>>(x, wm + l * DD, h);
        k_dequant<<<wFD / 1024, 256, 0, stream>>>(gatet + l * wFD, gates + l * sFD, wbuf);
        gemm_bf16<0><<<gF, 256, 0, stream>>>(h, wbuf, g, nullptr, nullptr, BSR, DFFD, DD);
        k_dequant<<<wFD / 1024, 256, 0, stream>>>(upt + l * wFD, ups + l * sFD, wbuf);
        gemm_bf16<2><<<gF, 256, 0, stream>>>(h, wbuf, nullptr, gb, g, BSR, DFFD, DD);
        k_dequant<<<wFD / 1024, 256, 0, stream>>>(downt + l * wFD, downs + l * sFD, wbuf);
        gemm_bf16<1><<<gD, 256, 0, stream>>>(gb, wbuf, x, nullptr, nullptr, BSR, DD, DFFD);
    }

    k_rmsnorm<<<BSR, 256, 0, stream>>>(x, wf, h);
    k_dequant<<<((size_t)VV * DD) / 1024, 256, 0, stream>>>(headt, heads, wbuf);
    gemm_bf16<0><<<gV, 256, 0, stream>>>(h, wbuf, (float*)d_out, nullptr, nullptr, BSR, VV, DD);
}